// Round 8
// baseline (1262.107 us; speedup 1.0000x reference)
//
#include <hip/hip_runtime.h>
#include <math.h>

// Sizes (fixed): B=32, T=100, S=100, H=512, E=256, V=30000, 4H=2048, M_log=3168

typedef __attribute__((ext_vector_type(8))) short short8v;  // 8 bf16 (4 VGPRs)
typedef __attribute__((ext_vector_type(4))) float f32x4;
typedef unsigned long long ull;

#define LSTM_BLOCKS 64
#define NTIL 235

__device__ __forceinline__ float sigf(float x){ return 1.0f/(1.0f + __expf(-x)); }
__device__ __forceinline__ float tanhc(float x){
  x = fminf(fmaxf(x, -15.f), 15.f);
  float e = __expf(2.f*x);
  return (e-1.f)/(e+1.f);
}
__device__ __forceinline__ short f2bf(float f){
  unsigned u = __float_as_uint(f);
  u = (u + 0x7fffu + ((u >> 16) & 1u)) >> 16;
  return (short)u;
}
__device__ __forceinline__ float bf2f(short s){
  return __uint_as_float(((unsigned)(unsigned short)s) << 16);
}

// ---------------------------------------------------------------------------
// prep: gate-permuted weights for BOTH LSTMs (blockIdx.y selects).
// o' = u*4 + g (source row g*512+u)
// ---------------------------------------------------------------------------
__global__ void prep_permute(
    const float* __restrict__ Wi_e, const float* __restrict__ Wh_e,
    const float* __restrict__ bi_e, const float* __restrict__ bh_e,
    const float* __restrict__ Wi_w, const float* __restrict__ Wh_w,
    const float* __restrict__ bi_w, const float* __restrict__ bh_w,
    short* __restrict__ WiPh_e, short* __restrict__ WhPh_e, float* __restrict__ biasP_e,
    short* __restrict__ WiPh_w, short* __restrict__ WhPh_w, float* __restrict__ biasP_w)
{
  const int z = blockIdx.y;
  const float* Wi = z ? Wi_w : Wi_e;
  const float* Wh = z ? Wh_w : Wh_e;
  const float* bi = z ? bi_w : bi_e;
  const float* bh = z ? bh_w : bh_e;
  short* WiPh = z ? WiPh_w : WiPh_e;
  short* WhPh = z ? WhPh_w : WhPh_e;
  float* biasP = z ? biasP_w : biasP_e;

  int idx = blockIdx.x*256 + threadIdx.x;      // 0 .. 1048575
  {
    int op = idx >> 9, k = idx & 511;
    int u = op >> 2, g = op & 3;
    WhPh[idx] = f2bf(Wh[(g*512+u)*512 + k]);
  }
  if (idx < 2048*256) {
    int op = idx >> 8, e = idx & 255;
    int u = op >> 2, g = op & 3;
    WiPh[idx] = f2bf(Wi[(g*512+u)*256 + e]);
  }
  if (idx < 2048) {
    int u = idx >> 2, g = idx & 3;
    biasP[idx] = bi[g*512+u] + bh[g*512+u];
  }
}

// ---------------------------------------------------------------------------
// misc prep: conv Wp (65536 x4-groups), conv Wm (131072), h0 -> hq[0] (8192),
// zero flags (128), edit counters (32 serial threads).
// ---------------------------------------------------------------------------
__global__ void misc_prep(const float* __restrict__ Wp, const float* __restrict__ Wm,
                          const float* __restrict__ h0, const int* __restrict__ ie,
                          short* __restrict__ Wph, short* __restrict__ Wmh,
                          ull* __restrict__ hq, unsigned* __restrict__ bar,
                          int* __restrict__ ctr_del, int* __restrict__ ctr_ins)
{
  int idx = blockIdx.x*256 + threadIdx.x;
  if (idx < 65536) {
    float4 v = *(const float4*)(Wp + (long)idx*4);
    short4 o; o.x=f2bf(v.x); o.y=f2bf(v.y); o.z=f2bf(v.z); o.w=f2bf(v.w);
    *(short4*)(Wph + (long)idx*4) = o;
  } else if (idx < 196608) {
    int i = idx - 65536;
    float4 v = *(const float4*)(Wm + (long)i*4);
    short4 o; o.x=f2bf(v.x); o.y=f2bf(v.y); o.z=f2bf(v.z); o.w=f2bf(v.w);
    *(short4*)(Wmh + (long)i*4) = o;
  } else if (idx < 204800) {
    int i = idx - 196608;                  // 0..8191 : l,b,q
    int b = (i >> 7) & 31, q = i & 127;
    const float* src = h0 + b*512 + q*4;
    ull v = ((ull)(unsigned short)f2bf(src[3]) << 48) |
            ((ull)(unsigned short)f2bf(src[2]) << 32) |
            ((ull)(unsigned short)f2bf(src[1]) << 16) |
            ((ull)(unsigned short)f2bf(src[0]));
    hq[i] = v;
  } else if (idx < 204928) {
    bar[idx - 204800] = 0u;
  } else if (idx < 204960) {
    int b = idx - 204928;
    int rd = 0, ri = 0;
    for (int t = 0; t < 99; ++t) {
      int a = ie[b*100 + t + 1];
      int incd = (a == 2 || a == 3) ? 1 : 0;
      int inci = (a != 3 && a != 5 && a != 0) ? 1 : 0;
      ctr_del[b*99 + t] = min(rd, 99);
      ctr_ins[b*99 + t] = min(ri, 99);
      rd += incd; ri += inci;
    }
  }
}

// f32 -> bf16 (RNE), n4 float4-groups
__global__ void conv_bf16(const float* __restrict__ src, short* __restrict__ dst, int n4)
{
  int i = blockIdx.x*256 + threadIdx.x;
  if (i >= n4) return;
  float4 v = *(const float4*)(src + (long)i*4);
  short4 o;
  o.x = f2bf(v.x); o.y = f2bf(v.y); o.z = f2bf(v.z); o.w = f2bf(v.w);
  *(short4*)(dst + (long)i*4) = o;
}

// ---------------------------------------------------------------------------
// bf16 MFMA GEMM body (shared): C[M,N] = act( A @ B^T + bias )
// ---------------------------------------------------------------------------
template<int GATHER,int CVT_A,int BIAS,int TANH,int OUT_BF16>
__device__ __forceinline__ void gemm_mfma_body(
    const void* __restrict__ Av, const int* __restrict__ tok,
    const short* __restrict__ Bh, const float* __restrict__ bias,
    void* __restrict__ Cv, int M, int N, int K, int lda, int ldc,
    int bxk, int byk)
{
  __shared__ short As[128][72];
  __shared__ short Bs[128][72];
  const int bm = bxk * 128;
  const int bn = byk * 128;
  const int tid = threadIdx.x;
  const int w = tid >> 6, l = tid & 63;
  const int wr = (w >> 1) * 64, wc = (w & 1) * 64;
  const int lr = l & 15, kg = l >> 4;

  f32x4 acc[4][4] = {};

  for (int k0 = 0; k0 < K; k0 += 64) {
    #pragma unroll
    for (int q = 0; q < 4; ++q) {
      int ci = tid + 256*q;
      int r = ci >> 3, ch = ci & 7;
      int ar = bm + r; if (ar > M-1) ar = M-1;
      if (GATHER) ar = tok[ar];
      if (CVT_A) {
        const float* ap = ((const float*)Av) + (long)ar*lda + k0 + ch*8;
        float4 v0 = *(const float4*)ap;
        float4 v1 = *(const float4*)(ap + 4);
        short8v s;
        s[0]=f2bf(v0.x); s[1]=f2bf(v0.y); s[2]=f2bf(v0.z); s[3]=f2bf(v0.w);
        s[4]=f2bf(v1.x); s[5]=f2bf(v1.y); s[6]=f2bf(v1.z); s[7]=f2bf(v1.w);
        *(short8v*)&As[r][ch*8] = s;
      } else {
        *(short8v*)&As[r][ch*8] =
            *(const short8v*)(((const short*)Av) + (long)ar*lda + k0 + ch*8);
      }
      int br = bn + r; if (br > N-1) br = N-1;
      *(short8v*)&Bs[r][ch*8] = *(const short8v*)(Bh + (long)br*K + k0 + ch*8);
    }
    __syncthreads();
    #pragma unroll
    for (int ks = 0; ks < 2; ++ks) {
      short8v a[4], b[4];
      #pragma unroll
      for (int m = 0; m < 4; ++m)
        a[m] = *(const short8v*)&As[wr + m*16 + lr][ks*32 + kg*8];
      #pragma unroll
      for (int n = 0; n < 4; ++n)
        b[n] = *(const short8v*)&Bs[wc + n*16 + lr][ks*32 + kg*8];
      #pragma unroll
      for (int m = 0; m < 4; ++m)
        #pragma unroll
        for (int n = 0; n < 4; ++n)
          acc[m][n] = __builtin_amdgcn_mfma_f32_16x16x32_bf16(a[m], b[n], acc[m][n], 0, 0, 0);
    }
    __syncthreads();
  }

  #pragma unroll
  for (int n = 0; n < 4; ++n) {
    int col = bn + wc + n*16 + lr;
    bool cok = (col < N);
    float bv = (BIAS && cok) ? bias[col] : 0.f;
    #pragma unroll
    for (int m = 0; m < 4; ++m) {
      int row0 = bm + wr + m*16 + kg*4;
      #pragma unroll
      for (int r = 0; r < 4; ++r) {
        int row = row0 + r;
        if (cok && row < M) {
          float v = acc[m][n][r] + bv;
          if (TANH) v = tanhc(v);
          if (OUT_BF16) ((short*)Cv)[(long)row*ldc + col] = f2bf(v);
          else          ((float*)Cv)[(long)row*ldc + col] = v;
        }
      }
    }
  }
}

template<int GATHER,int CVT_A,int BIAS,int TANH,int OUT_BF16>
__global__ __launch_bounds__(256) void gemm_mfma(
    const void* __restrict__ Av, const int* __restrict__ tok,
    const short* __restrict__ Bh, const float* __restrict__ bias,
    void* __restrict__ Cv, int M, int N, int K, int lda, int ldc)
{
  gemm_mfma_body<GATHER,CVT_A,BIAS,TANH,OUT_BF16>(
      Av, tok, Bh, bias, Cv, M, N, K, lda, ldc, blockIdx.x, blockIdx.y);
}

// both Xproj GEMMs in one launch (blockIdx.z selects LSTM)
__global__ __launch_bounds__(256) void xproj_mfma(
    const float* __restrict__ emb,
    const int* __restrict__ tokA, const int* __restrict__ tokB,
    const short* __restrict__ WA, const short* __restrict__ WB,
    const float* __restrict__ bA, const float* __restrict__ bB,
    float* __restrict__ outA, float* __restrict__ outB)
{
  const int z = blockIdx.z;
  gemm_mfma_body<1,1,1,0,0>(
      emb, z ? tokB : tokA, z ? WB : WA, z ? bB : bA,
      z ? (void*)outB : (void*)outA, 3200, 2048, 256, 256, 2048,
      blockIdx.x, blockIdx.y);
}

// ---------------------------------------------------------------------------
// logits GEMM + per-tile LSE partials, bf16 logits out.
// ---------------------------------------------------------------------------
__global__ __launch_bounds__(256) void logits_mfma_partial(
    const short* __restrict__ Ah,   // [3168][256] bf16
    const short* __restrict__ Bh,   // [30000][256] bf16
    const float* __restrict__ bias,
    short* __restrict__ Cg,         // [3168][30000] bf16 logits
    float2* __restrict__ partial)   // [3168][NTIL]
{
  __shared__ short As[128][72];
  __shared__ short Bs[128][72];
  __shared__ float2 red[128][2];
  const int bm = blockIdx.x * 128;
  const int bn = blockIdx.y * 128;
  const int tid = threadIdx.x;
  const int w = tid >> 6, l = tid & 63;
  const int wr = (w >> 1) * 64, wc = (w & 1) * 64;
  const int lr = l & 15, kg = l >> 4;

  f32x4 acc[4][4] = {};

  #pragma unroll
  for (int k0 = 0; k0 < 256; k0 += 64) {
    #pragma unroll
    for (int q = 0; q < 4; ++q) {
      int ci = tid + 256*q;
      int r = ci >> 3, ch = ci & 7;
      int ar = bm + r; if (ar > 3167) ar = 3167;
      *(short8v*)&As[r][ch*8] = *(const short8v*)(Ah + (long)ar*256 + k0 + ch*8);
      int br = bn + r; if (br > 29999) br = 29999;
      *(short8v*)&Bs[r][ch*8] = *(const short8v*)(Bh + (long)br*256 + k0 + ch*8);
    }
    __syncthreads();
    #pragma unroll
    for (int ks = 0; ks < 2; ++ks) {
      short8v a[4], b[4];
      #pragma unroll
      for (int m = 0; m < 4; ++m)
        a[m] = *(const short8v*)&As[wr + m*16 + lr][ks*32 + kg*8];
      #pragma unroll
      for (int n = 0; n < 4; ++n)
        b[n] = *(const short8v*)&Bs[wc + n*16 + lr][ks*32 + kg*8];
      #pragma unroll
      for (int m = 0; m < 4; ++m)
        #pragma unroll
        for (int n = 0; n < 4; ++n)
          acc[m][n] = __builtin_amdgcn_mfma_f32_16x16x32_bf16(a[m], b[n], acc[m][n], 0, 0, 0);
    }
    __syncthreads();
  }

  #pragma unroll
  for (int n = 0; n < 4; ++n) {
    int col = bn + wc + n*16 + lr;
    float bv = (col < 30000) ? bias[col] : 0.f;
    #pragma unroll
    for (int m = 0; m < 4; ++m)
      #pragma unroll
      for (int r = 0; r < 4; ++r)
        acc[m][n][r] = (col < 30000) ? acc[m][n][r] + bv : -INFINITY;
  }
  #pragma unroll
  for (int m = 0; m < 4; ++m) {
    #pragma unroll
    for (int r = 0; r < 4; ++r) {
      float a0 = acc[m][0][r], a1 = acc[m][1][r], a2 = acc[m][2][r], a3 = acc[m][3][r];
      float mx = fmaxf(fmaxf(a0, a1), fmaxf(a2, a3));
      #pragma unroll
      for (int off = 1; off < 16; off <<= 1) mx = fmaxf(mx, __shfl_xor(mx, off));
      float se = 0.f;
      if (mx > -INFINITY)
        se = __expf(a0-mx) + __expf(a1-mx) + __expf(a2-mx) + __expf(a3-mx);
      #pragma unroll
      for (int off = 1; off < 16; off <<= 1) se += __shfl_xor(se, off);
      if (lr == 0) red[wr + m*16 + kg*4 + r][w & 1] = make_float2(mx, se);
    }
  }
  #pragma unroll
  for (int n = 0; n < 4; ++n) {
    int col = bn + wc + n*16 + lr;
    if (col < 30000) {
      #pragma unroll
      for (int m = 0; m < 4; ++m) {
        int row0 = bm + wr + m*16 + kg*4;
        #pragma unroll
        for (int r = 0; r < 4; ++r) {
          int row = row0 + r;
          if (row < 3168) Cg[(long)row*30000 + col] = f2bf(acc[m][n][r]);
        }
      }
    }
  }
  __syncthreads();
  if (tid < 128) {
    int row = bm + tid;
    if (row < 3168) {
      float2 A = red[tid][0], B = red[tid][1];
      float M = fmaxf(A.x, B.x);
      float S = 0.f;
      if (M > -INFINITY) S = A.y*__expf(A.x - M) + B.y*__expf(B.x - M);
      partial[(long)row*NTIL + blockIdx.y] = make_float2(M, S);
    }
  }
}

// combine per-tile partials -> lse per row; one wave per row
__global__ void lse_reduce(const float2* __restrict__ partial, float* __restrict__ lse)
{
  int row  = blockIdx.x*4 + (threadIdx.x >> 6);
  int lane = threadIdx.x & 63;
  if (row >= 3168) return;
  const float2* pr = partial + (long)row*NTIL;
  float m = -INFINITY, s = 0.f;
  for (int tl = lane; tl < NTIL; tl += 64) {
    float2 p = pr[tl];
    float nm = fmaxf(m, p.x);
    if (nm > -INFINITY) {
      s = s*__expf(m - nm) + p.y*__expf(p.x - nm);
      m = nm;
    }
  }
  #pragma unroll
  for (int off = 32; off; off >>= 1) {
    float om = __shfl_xor(m, off);
    float os = __shfl_xor(s, off);
    float nm = fmaxf(m, om);
    if (nm > -INFINITY) {
      s = s*__expf(m - nm) + os*__expf(om - nm);
      m = nm;
    }
  }
  if (lane == 0) lse[row] = m + __logf(s);
}

// logp = bf16logit - lse
__global__ __launch_bounds__(256) void sub_lse_bf16(const short* __restrict__ Cg,
                                                    const float* __restrict__ lse,
                                                    float* __restrict__ out)
{
  int row = blockIdx.x;
  float lv = lse[row];
  const short* src = Cg + (long)row*30000;
  float* dst = out + (long)row*30000;
  for (int i = threadIdx.x; i < 3750; i += 256) {
    short8v v = *(const short8v*)(src + i*8);
    float4 o0, o1;
    o0.x = bf2f(v[0]) - lv; o0.y = bf2f(v[1]) - lv;
    o0.z = bf2f(v[2]) - lv; o0.w = bf2f(v[3]) - lv;
    o1.x = bf2f(v[4]) - lv; o1.y = bf2f(v[5]) - lv;
    o1.z = bf2f(v[6]) - lv; o1.w = bf2f(v[7]) - lv;
    *(float4*)(dst + i*8)     = o0;
    *(float4*)(dst + i*8 + 4) = o1;
  }
}

// ---------------------------------------------------------------------------
// Generic f32 GEMM (attention scores / applied only)
// ---------------------------------------------------------------------------
template<int TRANSB>
__global__ __launch_bounds__(256) void gemm_f32(
    const float* __restrict__ A, const float* __restrict__ Bmat,
    float* __restrict__ C,
    int M, int N, int K, int lda, int ldb, int ldc,
    long sA, long sB, long sC)
{
  __shared__ float As[32][68];
  __shared__ float Bs[32][68];
  const int z = blockIdx.z;
  A    += (long)z * sA;
  Bmat += (long)z * sB;
  C    += (long)z * sC;
  const int bm = blockIdx.y*64, bn = blockIdx.x*64;
  const int tid = threadIdx.x;
  const int tx = tid & 15, ty = tid >> 4;
  float acc[4][4] = {};

  for (int k0 = 0; k0 < K; k0 += 32) {
    {
      int r = tid >> 2;
      int c0 = (tid & 3) * 8;
      int row = bm + r; if (row > M-1) row = M-1;
      const float* ap = A + (long)row * lda;
      #pragma unroll
      for (int q = 0; q < 2; ++q) {
        int kk = c0 + q*4;
        float4 v;
        if (k0 + kk + 4 <= K) v = *(const float4*)(ap + k0 + kk);
        else {
          v.x = (k0+kk+0 < K) ? ap[k0+kk+0] : 0.f;
          v.y = (k0+kk+1 < K) ? ap[k0+kk+1] : 0.f;
          v.z = (k0+kk+2 < K) ? ap[k0+kk+2] : 0.f;
          v.w = (k0+kk+3 < K) ? ap[k0+kk+3] : 0.f;
        }
        As[kk+0][r]=v.x; As[kk+1][r]=v.y; As[kk+2][r]=v.z; As[kk+3][r]=v.w;
      }
    }
    if (TRANSB) {
      int n = tid >> 2;
      int c0 = (tid & 3) * 8;
      int col = bn + n; if (col > N-1) col = N-1;
      const float* bp = Bmat + (long)col * ldb;
      #pragma unroll
      for (int q = 0; q < 2; ++q) {
        int kk = c0 + q*4;
        float4 v;
        if (k0 + kk + 4 <= K) v = *(const float4*)(bp + k0 + kk);
        else {
          v.x = (k0+kk+0 < K) ? bp[k0+kk+0] : 0.f;
          v.y = (k0+kk+1 < K) ? bp[k0+kk+1] : 0.f;
          v.z = (k0+kk+2 < K) ? bp[k0+kk+2] : 0.f;
          v.w = (k0+kk+3 < K) ? bp[k0+kk+3] : 0.f;
        }
        Bs[kk+0][n]=v.x; Bs[kk+1][n]=v.y; Bs[kk+2][n]=v.z; Bs[kk+3][n]=v.w;
      }
    } else {
      int kk = tid >> 3;
      int c0 = (tid & 7) * 8;
      int krow = k0 + kk;
      #pragma unroll
      for (int q = 0; q < 2; ++q) {
        int cc = c0 + q*4;
        int col = bn + cc;
        float4 v = make_float4(0.f,0.f,0.f,0.f);
        if (krow < K) {
          const float* bp = Bmat + (long)krow * ldb;
          if (col + 4 <= N) v = *(const float4*)(bp + col);
          else {
            v.x = (col+0 < N) ? bp[col+0] : 0.f;
            v.y = (col+1 < N) ? bp[col+1] : 0.f;
            v.z = (col+2 < N) ? bp[col+2] : 0.f;
            v.w = (col+3 < N) ? bp[col+3] : 0.f;
          }
        }
        Bs[kk][cc+0]=v.x; Bs[kk][cc+1]=v.y; Bs[kk][cc+2]=v.z; Bs[kk][cc+3]=v.w;
      }
    }
    __syncthreads();
    #pragma unroll
    for (int kk = 0; kk < 32; ++kk) {
      float4 a = *(const float4*)&As[kk][ty*4];
      float4 b = *(const float4*)&Bs[kk][tx*4];
      acc[0][0]=fmaf(a.x,b.x,acc[0][0]); acc[0][1]=fmaf(a.x,b.y,acc[0][1]);
      acc[0][2]=fmaf(a.x,b.z,acc[0][2]); acc[0][3]=fmaf(a.x,b.w,acc[0][3]);
      acc[1][0]=fmaf(a.y,b.x,acc[1][0]); acc[1][1]=fmaf(a.y,b.y,acc[1][1]);
      acc[1][2]=fmaf(a.y,b.z,acc[1][2]); acc[1][3]=fmaf(a.y,b.w,acc[1][3]);
      acc[2][0]=fmaf(a.z,b.x,acc[2][0]); acc[2][1]=fmaf(a.z,b.y,acc[2][1]);
      acc[2][2]=fmaf(a.z,b.z,acc[2][2]); acc[2][3]=fmaf(a.z,b.w,acc[2][3]);
      acc[3][0]=fmaf(a.w,b.x,acc[3][0]); acc[3][1]=fmaf(a.w,b.y,acc[3][1]);
      acc[3][2]=fmaf(a.w,b.z,acc[3][2]); acc[3][3]=fmaf(a.w,b.w,acc[3][3]);
    }
    __syncthreads();
  }
  #pragma unroll
  for (int i = 0; i < 4; ++i) {
    int row = bm + ty*4 + i;
    if (row >= M) continue;
    #pragma unroll
    for (int j = 0; j < 4; ++j) {
      int col = bn + tx*4 + j;
      if (col >= N) continue;
      C[(long)row*ldc + col] = acc[i][j];
    }
  }
}

// ---------------------------------------------------------------------------
// Persistent LSTM recurrence v3 — no LDS, direct global B-frags.
// B-fragment of mfma_16x16x32 (lane bn,kg: h[bn][kg*8..+7], 16B) maps exactly
// onto the qword-packed hq[t] layout -> read straight from global (L3),
// eliminating LDS staging + one __syncthreads per step.
// outT stores moved AFTER flag publication so vmcnt(0) drains only h-stores.
// ---------------------------------------------------------------------------
__global__ __launch_bounds__(256, 1) void lstm_persist(
    const short* __restrict__ WhPh_e, const short* __restrict__ WhPh_w,
    const float* __restrict__ Xp_e, const float* __restrict__ Xp_w,
    const float* __restrict__ c0_in,
    ull* __restrict__ hq,        // [101][2][32][128] qwords
    short* __restrict__ outT,    // [2 lstm][100 t][512 u][32 b] bf16
    float* __restrict__ out_hc,  // he[32][512] then ce[32][512]
    unsigned* __restrict__ flags)// [0..63] per-block flags; [100] entry fence
{
  const int bx = blockIdx.x;
  const int l = bx >> 5;
  const int ublk = bx & 31;
  const int tid = threadIdx.x;
  const int w = tid >> 6, lane = tid & 63;
  const int uloc = lane >> 4;          // unit within wave (0..3); also k-group
  const int bn = lane & 15;            // batch (and bn+16)
  const int u_global = ublk*16 + w*4 + uloc;
  const int ob = (ublk*16 + w*4) * 4;  // o' base of wave
  const int qcol = ublk*4 + w;         // this wave's qword column

  const short* WhPh = l ? WhPh_w : WhPh_e;
  const float* Xp   = l ? Xp_w   : Xp_e;
  const unsigned* myfl = flags + l*32;

  // one-time agent acquire: no cross-replay stale lines in L1/L2
  __hip_atomic_load(&flags[100], __ATOMIC_ACQUIRE, __HIP_MEMORY_SCOPE_AGENT);

  // preload weight A-frags
  short8v afr[16];
  {
    const short* wp = WhPh + (long)(ob + bn)*512 + uloc*8;
    #pragma unroll
    for (int ks = 0; ks < 16; ++ks)
      afr[ks] = *(const short8v*)(wp + ks*32);
  }
  // persistent cell state
  float c_s0 = c0_in[bn*512 + u_global];
  float c_s1 = c0_in[(bn+16)*512 + u_global];

  for (int t = 0; t < 100; ++t) {
    // Xp gathers issued early (independent of flags)
    float4 x0 = *(const float4*)(Xp + ((long)(bn*100 + t))*2048 + u_global*4);
    float4 x1 = *(const float4*)(Xp + ((long)((bn+16)*100 + t))*2048 + u_global*4);
    // wait for all 32 producers of this lstm to have published h[t]
    if (t) {
      int ok;
      do {
        unsigned f = (lane < 32)
          ? __hip_atomic_load(&myfl[lane], __ATOMIC_RELAXED, __HIP_MEMORY_SCOPE_AGENT)
          : 0xffffffffu;
        ok = __all((int)(f >= (unsigned)t));
        if (!ok) __builtin_amdgcn_s_sleep(1);
      } while (!ok);
    }
    // direct global B-frag loads from this step's single-use buffer
    const ull* hsrc = hq + (size_t)t*8192 + (l << 12);
    const ull* r0 = hsrc + (bn << 7) + uloc*2;        // row bn,    k = uloc*8
    const ull* r1 = hsrc + ((bn+16) << 7) + uloc*2;   // row bn+16
    f32x4 acc0 = {}, acc1 = {};
    #pragma unroll
    for (int ks = 0; ks < 16; ++ks) {
      short8v b0 = *(const short8v*)(r0 + ks*8);      // +64B = k+32 units
      short8v b1 = *(const short8v*)(r1 + ks*8);
      acc0 = __builtin_amdgcn_mfma_f32_16x16x32_bf16(afr[ks], b0, acc0, 0, 0, 0);
      acc1 = __builtin_amdgcn_mfma_f32_16x16x32_bf16(afr[ks], b1, acc1, 0, 0, 0);
    }
    // cell update (lane-local: acc regs 0..3 = gates i,f,g,o of this unit)
    float gi = acc0[0] + x0.x, gf = acc0[1] + x0.y, gg = acc0[2] + x0.z, go = acc0[3] + x0.w;
    c_s0 = sigf(gf)*c_s0 + sigf(gi)*tanhc(gg);
    float hv0 = sigf(go)*tanhc(c_s0);
    gi = acc1[0] + x1.x; gf = acc1[1] + x1.y; gg = acc1[2] + x1.z; go = acc1[3] + x1.w;
    c_s1 = sigf(gf)*c_s1 + sigf(gi)*tanhc(gg);
    float hv1 = sigf(go)*tanhc(c_s1);

    short hb0 = f2bf(hv0), hb1 = f2bf(hv1);
    // pack 4 units (uloc 0..3 live in lanes bn, bn+16, bn+32, bn+48)
    unsigned p0 = (unsigned)(unsigned short)hb0;
    unsigned p1 = (unsigned)(unsigned short)hb1;
    unsigned a1 = __shfl_down((int)p0, 16), a2 = __shfl_down((int)p0, 32), a3 = __shfl_down((int)p0, 48);
    unsigned e1 = __shfl_down((int)p1, 16), e2 = __shfl_down((int)p1, 32), e3 = __shfl_down((int)p1, 48);
    if (uloc == 0) {
      ull q0 = ((ull)((a2 & 0xffffu) | (a3 << 16)) << 32) | ((p0 & 0xffffu) | (a1 << 16));
      ull q1 = ((ull)((e2 & 0xffffu) | (e3 << 16)) << 32) | ((p1 & 0xffffu) | (e1 << 16));
      ull* hd = hq + (size_t)(t+1)*8192 + (l << 12);
      __hip_atomic_store(&hd[(bn << 7) + qcol],      q0, __ATOMIC_RELAXED, __HIP_MEMORY_SCOPE_AGENT);
      __hip_atomic_store(&hd[((bn+16) << 7) + qcol], q1, __ATOMIC_RELAXED, __HIP_MEMORY_SCOPE_AGENT);
    }
    if (t < 99) {
      asm volatile("s_waitcnt vmcnt(0)" ::: "memory");  // own h-stores at L3
      __syncthreads();                                   // whole block drained
      if (tid == 0)
        __hip_atomic_store(&flags[bx], (unsigned)(t+1),
                           __ATOMIC_RELAXED, __HIP_MEMORY_SCOPE_AGENT);
    }
    // sequence output AFTER flag publication (off the critical path)
    short* od = outT + ((long)(l*100 + t)*512 + u_global)*32;
    od[bn]    = hb0;
    od[bn+16] = hb1;
    if (t == 99 && l == 0) {
      out_hc[bn*512 + u_global]              = hv0;
      out_hc[(bn+16)*512 + u_global]         = hv1;
      out_hc[16384 + bn*512 + u_global]      = c_s0;
      out_hc[16384 + (bn+16)*512 + u_global] = c_s1;
    }
  }
}

// transpose out sequences bf16 [lstm][t][u][b] -> bf16 [b][t][u]
__global__ __launch_bounds__(256) void transpose_out(
    const short* __restrict__ outT, short* __restrict__ out_e, short* __restrict__ out_w)
{
  __shared__ short tile[512][40];
  const int t = blockIdx.x, l = blockIdx.y;
  const short* src = outT + (long)(l*100 + t)*16384;
  const int tid = threadIdx.x;
  #pragma unroll
  for (int i = 0; i < 8; ++i) {
    int fi = tid + 256*i;
    int u = fi >> 2, b8 = (fi & 3)*8;
    *(short8v*)&tile[u][b8] = *(const short8v*)(src + fi*8);
  }
  __syncthreads();
  short* dst = l ? out_w : out_e;
  for (int b = 0; b < 32; ++b) {
    short* drow = dst + (long)(b*100 + t)*512;
    drow[tid]     = tile[tid][b];
    drow[tid+256] = tile[tid+256][b];
  }
}

__global__ void softmax_rows(float* __restrict__ P)
{
  int row  = blockIdx.x*4 + (threadIdx.x >> 6);
  int lane = threadIdx.x & 63;
  float* p = P + (long)row*128;
  float x0 = (lane      < 100) ? p[lane]    : -INFINITY;
  float x1 = (lane + 64 < 100) ? p[lane+64] : -INFINITY;
  float m = fmaxf(x0, x1);
  #pragma unroll
  for (int off = 32; off; off >>= 1) m = fmaxf(m, __shfl_xor(m, off));
  float e0 = (lane      < 100) ? __expf(x0 - m) : 0.f;
  float e1 = (lane + 64 < 100) ? __expf(x1 - m) : 0.f;
  float s = e0 + e1;
  #pragma unroll
  for (int off = 32; off; off >>= 1) s += __shfl_xor(s, off);
  float inv = 1.f / s;
  if (lane      < 100) p[lane]    = e0 * inv;
  if (lane + 64 < 100) p[lane+64] = e1 * inv;
}

// build bf16 feat rows [3168][2048] = [out_e | applied | enc[ctr_del] | out_w[ctr_ins]]
__global__ void feat_kernel(const short* __restrict__ out_e, const float* __restrict__ applied,
                            const float* __restrict__ enc,  const short* __restrict__ out_w,
                            const int* __restrict__ ctr_del, const int* __restrict__ ctr_ins,
                            short* __restrict__ feat)
{
  int n = blockIdx.x;                 // 0..3167
  int b = n / 99, t = n % 99;
  int tid = threadIdx.x;
  int seg = tid >> 6;
  int off = (tid & 63) * 8;
  short8v v;
  if (seg == 0) {
    v = *(const short8v*)(out_e + (long)(b*100 + t)*512 + off);
  } else if (seg == 3) {
    v = *(const short8v*)(out_w + (long)(b*100 + ctr_ins[n])*512 + off);
  } else {
    const float* s = (seg == 1) ? applied + (long)(b*100 + t)*512
                                : enc     + (long)(b*100 + ctr_del[n])*512;
    float4 v0 = *(const float4*)(s + off);
    float4 v1 = *(const float4*)(s + off + 4);
    v[0]=f2bf(v0.x); v[1]=f2bf(v0.y); v[2]=f2bf(v0.z); v[3]=f2bf(v0.w);
    v[4]=f2bf(v1.x); v[5]=f2bf(v1.y); v[6]=f2bf(v1.z); v[7]=f2bf(v1.w);
  }
  *(short8v*)(feat + (long)n*2048 + seg*512 + off) = v;
}

// ---------------------------------------------------------------------------
extern "C" void kernel_launch(void* const* d_in, const int* in_sizes, int n_in,
                              void* d_out, int out_size, void* d_ws, size_t ws_size,
                              hipStream_t stream)
{
  const int*   input_edits = (const int*)  d_in[0];
  const int*   simp_sent   = (const int*)  d_in[1];
  const float* enc   = (const float*)d_in[3];
  const float* h0    = (const float*)d_in[4];
  const float* c0    = (const float*)d_in[5];
  const float* emb   = (const float*)d_in[6];
  const float* Wi_e  = (const float*)d_in[7];
  const float* Wh_e  = (const float*)d_in[8];
  const float* bi_e  = (const float*)d_in[9];
  const float* bh_e  = (const float*)d_in[10];
  const float* Wi_w  = (const float*)d_in[11];
  const float* Wh_w  = (const float*)d_in[12];
  const float* bi_w  = (const float*)d_in[13];
  const float* bh_w  = (const float*)d_in[14];
  const float* Wp    = (const float*)d_in[15];
  const float* Wm    = (const float*)d_in[16];
  const float* bmv   = (const float*)d_in[17];
  const float* b_out = (const float*)d_in[18];
  float* out = (float*)d_out;

  float* ws = (float*)d_ws;
  size_t off = 0;
  auto alloc = [&](size_t n){ float* p = ws + off; off += (n + 63) & ~(size_t)63; return p; };

  short* WiPh_e   = (short*)alloc(262144);   // 2048*256 bf16
  short* WiPh_w   = (short*)alloc(262144);
  float* biasP_e  = alloc(2048);
  float* biasP_w  = alloc(2048);
  short* WhPh_e   = (short*)alloc(524288);   // 2048*512 bf16
  short* WhPh_w   = (short*)alloc(524288);
  float* Xp_e     = alloc(3200*2048);
  float* Xp_w     = alloc(3200*2048);
  short* outT     = (short*)alloc(1638400);  // 2*100*512*32 bf16
  short* out_e    = (short*)alloc(819200);   // 3200*512 bf16
  short* out_w    = (short*)alloc(819200);
  ull*   hq       = (ull*)alloc(101*8192*2); // 101 step buffers x 64KB
  unsigned* bar   = (unsigned*)alloc(128);   // flags[0..63] + entry slot [100]
  float* Pbuf     = alloc(3200*128);
  float* lse      = alloc(3168);
  int*   ctr_del  = (int*)alloc(3168);
  int*   ctr_ins  = (int*)alloc(3168);
  short* Wph      = (short*)alloc(131072);   // 512*512 bf16
  short* Wmh      = (short*)alloc(262144);   // 256*2048 bf16
  float* key      = alloc(3200*512);
  float* applied  = alloc(3200*512);
  short* logith   = (short*)alloc(47520000); // 3168*30000 bf16 logits (190MB)
  float2* partial = (float2*)alloc(3168*NTIL*2);
  // overlays (lifetimes disjoint, stream-ordered):
  short* feath    = (short*)Xp_e;            // 3168*2048 bf16, after recurrence
  short* hmlph    = (short*)Xp_w;            // 3168*256 bf16, after MLP
  short* embh     = (short*)(Xp_w + 1048576);// 30000*256 bf16

  // 1) weight prep (both LSTMs) + misc prep (convs, h0, flags, counters)
  prep_permute<<<dim3(4096,2), 256, 0, stream>>>(
      Wi_e, Wh_e, bi_e, bh_e, Wi_w, Wh_w, bi_w, bh_w,
      WiPh_e, WhPh_e, biasP_e, WiPh_w, WhPh_w, biasP_w);
  misc_prep<<<801, 256, 0, stream>>>(Wp, Wm, h0, input_edits,
                                     Wph, Wmh, hq, bar, ctr_del, ctr_ins);

  // 2) Xproj both LSTMs, one launch
  xproj_mfma<<<dim3(25,16,2), 256, 0, stream>>>(
      emb, input_edits, simp_sent, WiPh_e, WiPh_w, biasP_e, biasP_w, Xp_e, Xp_w);

  // 3) recurrence: ONE persistent kernel, producer-flag sync, no LDS
  lstm_persist<<<LSTM_BLOCKS, 256, 0, stream>>>(
      WhPh_e, WhPh_w, Xp_e, Xp_w, c0, hq, outT, out + 95040000L, bar);

  // emb -> bf16 into Xp_w overlay (Xp_w dead after recurrence)
  conv_bf16<<<7500, 256, 0, stream>>>(emb, embh, 30000*256/4);

  // 4) transpose sequences to bf16 [b][t][u]
  transpose_out<<<dim3(100,2), 256, 0, stream>>>(outT, out_e, out_w);

  // 5) key = out_e @ Wp^T  (MFMA)
  gemm_mfma<0,0,0,0,0><<<dim3(25,4), 256, 0, stream>>>(
      out_e, nullptr, Wph, nullptr, key, 3200, 512, 512, 512, 512);

  // 6) attention (f32)
  gemm_f32<1><<<dim3(2,2,32), 256, 0, stream>>>(
      key, enc, Pbuf, 100, 100, 512, 512, 512, 128, 51200, 51200, 12800);
  softmax_rows<<<800, 256, 0, stream>>>(Pbuf);
  gemm_f32<0><<<dim3(8,2,32), 256, 0, stream>>>(
      Pbuf, enc, applied, 100, 512, 100, 128, 512, 512, 12800, 51200, 51200);

  // 7) feat(bf16) + MLP(MFMA, tanh, bf16 out)
  feat_kernel<<<3168, 256, 0, stream>>>(out_e, applied, enc, out_w, ctr_del, ctr_ins, feath);
  gemm_mfma<0,0,1,1,1><<<dim3(25,2), 256, 0, stream>>>(
      feath, nullptr, Wmh, bmv, hmlph, 3168, 256, 2048, 2048, 256);

  // 8) logits (MFMA, bf16 out + LSE partials) + log-softmax
  logits_mfma_partial<<<dim3(25, NTIL), 256, 0, stream>>>(
      hmlph, embh, b_out, logith, partial);
  lse_reduce<<<792, 256, 0, stream>>>(partial, lse);
  sub_lse_bf16<<<3168, 256, 0, stream>>>(logith, lse, out);
}

// Round 9
// 1008.638 us; speedup vs baseline: 1.2513x; 1.2513x over previous
//
#include <hip/hip_runtime.h>
#include <math.h>

// Sizes (fixed): B=32, T=100, S=100, H=512, E=256, V=30000, 4H=2048, M_log=3168

typedef __attribute__((ext_vector_type(8))) short short8v;  // 8 bf16 (4 VGPRs)
typedef __attribute__((ext_vector_type(4))) float f32x4;
typedef unsigned long long ull;

#define LSTM_BLOCKS 64
#define NTIL 235

__device__ __forceinline__ float sigf(float x){ return 1.0f/(1.0f + __expf(-x)); }
__device__ __forceinline__ float tanhc(float x){
  x = fminf(fmaxf(x, -15.f), 15.f);
  float e = __expf(2.f*x);
  return (e-1.f)/(e+1.f);
}
__device__ __forceinline__ short f2bf(float f){
  unsigned u = __float_as_uint(f);
  u = (u + 0x7fffu + ((u >> 16) & 1u)) >> 16;
  return (short)u;
}
__device__ __forceinline__ float bf2f(short s){
  return __uint_as_float(((unsigned)(unsigned short)s) << 16);
}

// ---------------------------------------------------------------------------
// prep: gate-permuted weights for BOTH LSTMs (blockIdx.y selects).
// o' = u*4 + g (source row g*512+u)
// ---------------------------------------------------------------------------
__global__ void prep_permute(
    const float* __restrict__ Wi_e, const float* __restrict__ Wh_e,
    const float* __restrict__ bi_e, const float* __restrict__ bh_e,
    const float* __restrict__ Wi_w, const float* __restrict__ Wh_w,
    const float* __restrict__ bi_w, const float* __restrict__ bh_w,
    short* __restrict__ WiPh_e, short* __restrict__ WhPh_e, float* __restrict__ biasP_e,
    short* __restrict__ WiPh_w, short* __restrict__ WhPh_w, float* __restrict__ biasP_w)
{
  const int z = blockIdx.y;
  const float* Wi = z ? Wi_w : Wi_e;
  const float* Wh = z ? Wh_w : Wh_e;
  const float* bi = z ? bi_w : bi_e;
  const float* bh = z ? bh_w : bh_e;
  short* WiPh = z ? WiPh_w : WiPh_e;
  short* WhPh = z ? WhPh_w : WhPh_e;
  float* biasP = z ? biasP_w : biasP_e;

  int idx = blockIdx.x*256 + threadIdx.x;      // 0 .. 1048575
  {
    int op = idx >> 9, k = idx & 511;
    int u = op >> 2, g = op & 3;
    WhPh[idx] = f2bf(Wh[(g*512+u)*512 + k]);
  }
  if (idx < 2048*256) {
    int op = idx >> 8, e = idx & 255;
    int u = op >> 2, g = op & 3;
    WiPh[idx] = f2bf(Wi[(g*512+u)*256 + e]);
  }
  if (idx < 2048) {
    int u = idx >> 2, g = idx & 3;
    biasP[idx] = bi[g*512+u] + bh[g*512+u];
  }
}

// ---------------------------------------------------------------------------
// misc prep: conv Wp, conv Wm, h0 -> hq[0], zero flags, edit counters
// ---------------------------------------------------------------------------
__global__ void misc_prep(const float* __restrict__ Wp, const float* __restrict__ Wm,
                          const float* __restrict__ h0, const int* __restrict__ ie,
                          short* __restrict__ Wph, short* __restrict__ Wmh,
                          ull* __restrict__ hq, unsigned* __restrict__ bar,
                          int* __restrict__ ctr_del, int* __restrict__ ctr_ins)
{
  int idx = blockIdx.x*256 + threadIdx.x;
  if (idx < 65536) {
    float4 v = *(const float4*)(Wp + (long)idx*4);
    short4 o; o.x=f2bf(v.x); o.y=f2bf(v.y); o.z=f2bf(v.z); o.w=f2bf(v.w);
    *(short4*)(Wph + (long)idx*4) = o;
  } else if (idx < 196608) {
    int i = idx - 65536;
    float4 v = *(const float4*)(Wm + (long)i*4);
    short4 o; o.x=f2bf(v.x); o.y=f2bf(v.y); o.z=f2bf(v.z); o.w=f2bf(v.w);
    *(short4*)(Wmh + (long)i*4) = o;
  } else if (idx < 204800) {
    int i = idx - 196608;                  // 0..8191 : l,b,q
    int b = (i >> 7) & 31, q = i & 127;
    const float* src = h0 + b*512 + q*4;
    ull v = ((ull)(unsigned short)f2bf(src[3]) << 48) |
            ((ull)(unsigned short)f2bf(src[2]) << 32) |
            ((ull)(unsigned short)f2bf(src[1]) << 16) |
            ((ull)(unsigned short)f2bf(src[0]));
    hq[i] = v;
  } else if (idx < 204928) {
    bar[idx - 204800] = 0u;
  } else if (idx < 204960) {
    int b = idx - 204928;
    int rd = 0, ri = 0;
    for (int t = 0; t < 99; ++t) {
      int a = ie[b*100 + t + 1];
      int incd = (a == 2 || a == 3) ? 1 : 0;
      int inci = (a != 3 && a != 5 && a != 0) ? 1 : 0;
      ctr_del[b*99 + t] = min(rd, 99);
      ctr_ins[b*99 + t] = min(ri, 99);
      rd += incd; ri += inci;
    }
  }
}

// ---------------------------------------------------------------------------
// bf16 MFMA GEMM body (shared): C[M,N] = act( A @ B^T + bias )
// ---------------------------------------------------------------------------
template<int GATHER,int CVT_A,int BIAS,int TANH,int OUT_BF16>
__device__ __forceinline__ void gemm_mfma_body(
    const void* __restrict__ Av, const int* __restrict__ tok,
    const short* __restrict__ Bh, const float* __restrict__ bias,
    void* __restrict__ Cv, int M, int N, int K, int lda, int ldc,
    int bxk, int byk)
{
  __shared__ short As[128][72];
  __shared__ short Bs[128][72];
  const int bm = bxk * 128;
  const int bn = byk * 128;
  const int tid = threadIdx.x;
  const int w = tid >> 6, l = tid & 63;
  const int wr = (w >> 1) * 64, wc = (w & 1) * 64;
  const int lr = l & 15, kg = l >> 4;

  f32x4 acc[4][4] = {};

  for (int k0 = 0; k0 < K; k0 += 64) {
    #pragma unroll
    for (int q = 0; q < 4; ++q) {
      int ci = tid + 256*q;
      int r = ci >> 3, ch = ci & 7;
      int ar = bm + r; if (ar > M-1) ar = M-1;
      if (GATHER) ar = tok[ar];
      if (CVT_A) {
        const float* ap = ((const float*)Av) + (long)ar*lda + k0 + ch*8;
        float4 v0 = *(const float4*)ap;
        float4 v1 = *(const float4*)(ap + 4);
        short8v s;
        s[0]=f2bf(v0.x); s[1]=f2bf(v0.y); s[2]=f2bf(v0.z); s[3]=f2bf(v0.w);
        s[4]=f2bf(v1.x); s[5]=f2bf(v1.y); s[6]=f2bf(v1.z); s[7]=f2bf(v1.w);
        *(short8v*)&As[r][ch*8] = s;
      } else {
        *(short8v*)&As[r][ch*8] =
            *(const short8v*)(((const short*)Av) + (long)ar*lda + k0 + ch*8);
      }
      int br = bn + r; if (br > N-1) br = N-1;
      *(short8v*)&Bs[r][ch*8] = *(const short8v*)(Bh + (long)br*K + k0 + ch*8);
    }
    __syncthreads();
    #pragma unroll
    for (int ks = 0; ks < 2; ++ks) {
      short8v a[4], b[4];
      #pragma unroll
      for (int m = 0; m < 4; ++m)
        a[m] = *(const short8v*)&As[wr + m*16 + lr][ks*32 + kg*8];
      #pragma unroll
      for (int n = 0; n < 4; ++n)
        b[n] = *(const short8v*)&Bs[wc + n*16 + lr][ks*32 + kg*8];
      #pragma unroll
      for (int m = 0; m < 4; ++m)
        #pragma unroll
        for (int n = 0; n < 4; ++n)
          acc[m][n] = __builtin_amdgcn_mfma_f32_16x16x32_bf16(a[m], b[n], acc[m][n], 0, 0, 0);
    }
    __syncthreads();
  }

  #pragma unroll
  for (int n = 0; n < 4; ++n) {
    int col = bn + wc + n*16 + lr;
    bool cok = (col < N);
    float bv = (BIAS && cok) ? bias[col] : 0.f;
    #pragma unroll
    for (int m = 0; m < 4; ++m) {
      int row0 = bm + wr + m*16 + kg*4;
      #pragma unroll
      for (int r = 0; r < 4; ++r) {
        int row = row0 + r;
        if (cok && row < M) {
          float v = acc[m][n][r] + bv;
          if (TANH) v = tanhc(v);
          if (OUT_BF16) ((short*)Cv)[(long)row*ldc + col] = f2bf(v);
          else          ((float*)Cv)[(long)row*ldc + col] = v;
        }
      }
    }
  }
}

template<int GATHER,int CVT_A,int BIAS,int TANH,int OUT_BF16>
__global__ __launch_bounds__(256) void gemm_mfma(
    const void* __restrict__ Av, const int* __restrict__ tok,
    const short* __restrict__ Bh, const float* __restrict__ bias,
    void* __restrict__ Cv, int M, int N, int K, int lda, int ldc)
{
  gemm_mfma_body<GATHER,CVT_A,BIAS,TANH,OUT_BF16>(
      Av, tok, Bh, bias, Cv, M, N, K, lda, ldc, blockIdx.x, blockIdx.y);
}

// both Xproj GEMMs in one launch (blockIdx.z selects LSTM); bf16 output
__global__ __launch_bounds__(256) void xproj_mfma(
    const float* __restrict__ emb,
    const int* __restrict__ tokA, const int* __restrict__ tokB,
    const short* __restrict__ WA, const short* __restrict__ WB,
    const float* __restrict__ bA, const float* __restrict__ bB,
    short* __restrict__ outA, short* __restrict__ outB)
{
  const int z = blockIdx.z;
  gemm_mfma_body<1,1,1,0,1>(
      emb, z ? tokB : tokA, z ? WB : WA, z ? bB : bA,
      z ? (void*)outB : (void*)outA, 3200, 2048, 256, 256, 2048,
      blockIdx.x, blockIdx.y);
}

// ---------------------------------------------------------------------------
// logits GEMM + per-tile LSE partials; A bf16, B staged from f32 emb w/ cvt;
// bf16 logits out.
// ---------------------------------------------------------------------------
__global__ __launch_bounds__(256) void logits_mfma_partial(
    const short* __restrict__ Ah,   // [3168][256] bf16
    const float* __restrict__ Bf,   // [30000][256] f32 emb
    const float* __restrict__ bias,
    short* __restrict__ Cg,         // [3168][30000] bf16 logits
    float2* __restrict__ partial)   // [3168][NTIL]
{
  __shared__ short As[128][72];
  __shared__ short Bs[128][72];
  __shared__ float2 red[128][2];
  const int bm = blockIdx.x * 128;
  const int bn = blockIdx.y * 128;
  const int tid = threadIdx.x;
  const int w = tid >> 6, l = tid & 63;
  const int wr = (w >> 1) * 64, wc = (w & 1) * 64;
  const int lr = l & 15, kg = l >> 4;

  f32x4 acc[4][4] = {};

  #pragma unroll
  for (int k0 = 0; k0 < 256; k0 += 64) {
    #pragma unroll
    for (int q = 0; q < 4; ++q) {
      int ci = tid + 256*q;
      int r = ci >> 3, ch = ci & 7;
      int ar = bm + r; if (ar > 3167) ar = 3167;
      *(short8v*)&As[r][ch*8] = *(const short8v*)(Ah + (long)ar*256 + k0 + ch*8);
      int br = bn + r; if (br > 29999) br = 29999;
      const float* bp = Bf + (long)br*256 + k0 + ch*8;
      float4 v0 = *(const float4*)bp;
      float4 v1 = *(const float4*)(bp + 4);
      short8v s;
      s[0]=f2bf(v0.x); s[1]=f2bf(v0.y); s[2]=f2bf(v0.z); s[3]=f2bf(v0.w);
      s[4]=f2bf(v1.x); s[5]=f2bf(v1.y); s[6]=f2bf(v1.z); s[7]=f2bf(v1.w);
      *(short8v*)&Bs[r][ch*8] = s;
    }
    __syncthreads();
    #pragma unroll
    for (int ks = 0; ks < 2; ++ks) {
      short8v a[4], b[4];
      #pragma unroll
      for (int m = 0; m < 4; ++m)
        a[m] = *(const short8v*)&As[wr + m*16 + lr][ks*32 + kg*8];
      #pragma unroll
      for (int n = 0; n < 4; ++n)
        b[n] = *(const short8v*)&Bs[wc + n*16 + lr][ks*32 + kg*8];
      #pragma unroll
      for (int m = 0; m < 4; ++m)
        #pragma unroll
        for (int n = 0; n < 4; ++n)
          acc[m][n] = __builtin_amdgcn_mfma_f32_16x16x32_bf16(a[m], b[n], acc[m][n], 0, 0, 0);
    }
    __syncthreads();
  }

  #pragma unroll
  for (int n = 0; n < 4; ++n) {
    int col = bn + wc + n*16 + lr;
    float bv = (col < 30000) ? bias[col] : 0.f;
    #pragma unroll
    for (int m = 0; m < 4; ++m)
      #pragma unroll
      for (int r = 0; r < 4; ++r)
        acc[m][n][r] = (col < 30000) ? acc[m][n][r] + bv : -INFINITY;
  }
  #pragma unroll
  for (int m = 0; m < 4; ++m) {
    #pragma unroll
    for (int r = 0; r < 4; ++r) {
      float a0 = acc[m][0][r], a1 = acc[m][1][r], a2 = acc[m][2][r], a3 = acc[m][3][r];
      float mx = fmaxf(fmaxf(a0, a1), fmaxf(a2, a3));
      #pragma unroll
      for (int off = 1; off < 16; off <<= 1) mx = fmaxf(mx, __shfl_xor(mx, off));
      float se = 0.f;
      if (mx > -INFINITY)
        se = __expf(a0-mx) + __expf(a1-mx) + __expf(a2-mx) + __expf(a3-mx);
      #pragma unroll
      for (int off = 1; off < 16; off <<= 1) se += __shfl_xor(se, off);
      if (lr == 0) red[wr + m*16 + kg*4 + r][w & 1] = make_float2(mx, se);
    }
  }
  #pragma unroll
  for (int n = 0; n < 4; ++n) {
    int col = bn + wc + n*16 + lr;
    if (col < 30000) {
      #pragma unroll
      for (int m = 0; m < 4; ++m) {
        int row0 = bm + wr + m*16 + kg*4;
        #pragma unroll
        for (int r = 0; r < 4; ++r) {
          int row = row0 + r;
          if (row < 3168) Cg[(long)row*30000 + col] = f2bf(acc[m][n][r]);
        }
      }
    }
  }
  __syncthreads();
  if (tid < 128) {
    int row = bm + tid;
    if (row < 3168) {
      float2 A = red[tid][0], B = red[tid][1];
      float M = fmaxf(A.x, B.x);
      float S = 0.f;
      if (M > -INFINITY) S = A.y*__expf(A.x - M) + B.y*__expf(B.x - M);
      partial[(long)row*NTIL + blockIdx.y] = make_float2(M, S);
    }
  }
}

// fused: per-row LSE from partials, then logp = bf16logit - lse
__global__ __launch_bounds__(256) void sub_lse_fused(
    const short* __restrict__ Cg, const float2* __restrict__ partial,
    float* __restrict__ out)
{
  int row = blockIdx.x;
  int tid = threadIdx.x;
  float m = -INFINITY, s = 0.f;
  if (tid < NTIL) {
    float2 p = partial[(long)row*NTIL + tid];
    m = p.x; s = p.y;
  }
  #pragma unroll
  for (int off = 32; off; off >>= 1) {
    float om = __shfl_xor(m, off);
    float os = __shfl_xor(s, off);
    float nm = fmaxf(m, om);
    if (nm > -INFINITY) {
      s = s*__expf(m - nm) + os*__expf(om - nm);
      m = nm;
    }
  }
  __shared__ float sm[4], ss[4], lsh;
  int wv = tid >> 6;
  if ((tid & 63) == 0) { sm[wv] = m; ss[wv] = s; }
  __syncthreads();
  if (tid == 0) {
    float M = sm[0], S = ss[0];
    #pragma unroll
    for (int i = 1; i < 4; ++i) {
      float nm = fmaxf(M, sm[i]);
      S = S*__expf(M - nm) + ss[i]*__expf(sm[i] - nm);
      M = nm;
    }
    lsh = M + __logf(S);
  }
  __syncthreads();
  float lv = lsh;
  const short* src = Cg + (long)row*30000;
  float* dst = out + (long)row*30000;
  for (int i = tid; i < 3750; i += 256) {
    short8v v = *(const short8v*)(src + i*8);
    float4 o0, o1;
    o0.x = bf2f(v[0]) - lv; o0.y = bf2f(v[1]) - lv;
    o0.z = bf2f(v[2]) - lv; o0.w = bf2f(v[3]) - lv;
    o1.x = bf2f(v[4]) - lv; o1.y = bf2f(v[5]) - lv;
    o1.z = bf2f(v[6]) - lv; o1.w = bf2f(v[7]) - lv;
    *(float4*)(dst + i*8)     = o0;
    *(float4*)(dst + i*8 + 4) = o1;
  }
}

// ---------------------------------------------------------------------------
// Generic f32 GEMM (attention scores / applied only)
// ---------------------------------------------------------------------------
template<int TRANSB>
__global__ __launch_bounds__(256) void gemm_f32(
    const float* __restrict__ A, const float* __restrict__ Bmat,
    float* __restrict__ C,
    int M, int N, int K, int lda, int ldb, int ldc,
    long sA, long sB, long sC)
{
  __shared__ float As[32][68];
  __shared__ float Bs[32][68];
  const int z = blockIdx.z;
  A    += (long)z * sA;
  Bmat += (long)z * sB;
  C    += (long)z * sC;
  const int bm = blockIdx.y*64, bn = blockIdx.x*64;
  const int tid = threadIdx.x;
  const int tx = tid & 15, ty = tid >> 4;
  float acc[4][4] = {};

  for (int k0 = 0; k0 < K; k0 += 32) {
    {
      int r = tid >> 2;
      int c0 = (tid & 3) * 8;
      int row = bm + r; if (row > M-1) row = M-1;
      const float* ap = A + (long)row * lda;
      #pragma unroll
      for (int q = 0; q < 2; ++q) {
        int kk = c0 + q*4;
        float4 v;
        if (k0 + kk + 4 <= K) v = *(const float4*)(ap + k0 + kk);
        else {
          v.x = (k0+kk+0 < K) ? ap[k0+kk+0] : 0.f;
          v.y = (k0+kk+1 < K) ? ap[k0+kk+1] : 0.f;
          v.z = (k0+kk+2 < K) ? ap[k0+kk+2] : 0.f;
          v.w = (k0+kk+3 < K) ? ap[k0+kk+3] : 0.f;
        }
        As[kk+0][r]=v.x; As[kk+1][r]=v.y; As[kk+2][r]=v.z; As[kk+3][r]=v.w;
      }
    }
    if (TRANSB) {
      int n = tid >> 2;
      int c0 = (tid & 3) * 8;
      int col = bn + n; if (col > N-1) col = N-1;
      const float* bp = Bmat + (long)col * ldb;
      #pragma unroll
      for (int q = 0; q < 2; ++q) {
        int kk = c0 + q*4;
        float4 v;
        if (k0 + kk + 4 <= K) v = *(const float4*)(bp + k0 + kk);
        else {
          v.x = (k0+kk+0 < K) ? bp[k0+kk+0] : 0.f;
          v.y = (k0+kk+1 < K) ? bp[k0+kk+1] : 0.f;
          v.z = (k0+kk+2 < K) ? bp[k0+kk+2] : 0.f;
          v.w = (k0+kk+3 < K) ? bp[k0+kk+3] : 0.f;
        }
        Bs[kk+0][n]=v.x; Bs[kk+1][n]=v.y; Bs[kk+2][n]=v.z; Bs[kk+3][n]=v.w;
      }
    } else {
      int kk = tid >> 3;
      int c0 = (tid & 7) * 8;
      int krow = k0 + kk;
      #pragma unroll
      for (int q = 0; q < 2; ++q) {
        int cc = c0 + q*4;
        int col = bn + cc;
        float4 v = make_float4(0.f,0.f,0.f,0.f);
        if (krow < K) {
          const float* bp = Bmat + (long)krow * ldb;
          if (col + 4 <= N) v = *(const float4*)(bp + col);
          else {
            v.x = (col+0 < N) ? bp[col+0] : 0.f;
            v.y = (col+1 < N) ? bp[col+1] : 0.f;
            v.z = (col+2 < N) ? bp[col+2] : 0.f;
            v.w = (col+3 < N) ? bp[col+3] : 0.f;
          }
        }
        Bs[kk][cc+0]=v.x; Bs[kk][cc+1]=v.y; Bs[kk][cc+2]=v.z; Bs[kk][cc+3]=v.w;
      }
    }
    __syncthreads();
    #pragma unroll
    for (int kk = 0; kk < 32; ++kk) {
      float4 a = *(const float4*)&As[kk][ty*4];
      float4 b = *(const float4*)&Bs[kk][tx*4];
      acc[0][0]=fmaf(a.x,b.x,acc[0][0]); acc[0][1]=fmaf(a.x,b.y,acc[0][1]);
      acc[0][2]=fmaf(a.x,b.z,acc[0][2]); acc[0][3]=fmaf(a.x,b.w,acc[0][3]);
      acc[1][0]=fmaf(a.y,b.x,acc[1][0]); acc[1][1]=fmaf(a.y,b.y,acc[1][1]);
      acc[1][2]=fmaf(a.y,b.z,acc[1][2]); acc[1][3]=fmaf(a.y,b.w,acc[1][3]);
      acc[2][0]=fmaf(a.z,b.x,acc[2][0]); acc[2][1]=fmaf(a.z,b.y,acc[2][1]);
      acc[2][2]=fmaf(a.z,b.z,acc[2][2]); acc[2][3]=fmaf(a.z,b.w,acc[2][3]);
      acc[3][0]=fmaf(a.w,b.x,acc[3][0]); acc[3][1]=fmaf(a.w,b.y,acc[3][1]);
      acc[3][2]=fmaf(a.w,b.z,acc[3][2]); acc[3][3]=fmaf(a.w,b.w,acc[3][3]);
    }
    __syncthreads();
  }
  #pragma unroll
  for (int i = 0; i < 4; ++i) {
    int row = bm + ty*4 + i;
    if (row >= M) continue;
    #pragma unroll
    for (int j = 0; j < 4; ++j) {
      int col = bn + tx*4 + j;
      if (col >= N) continue;
      C[(long)row*ldc + col] = acc[i][j];
    }
  }
}

// ---------------------------------------------------------------------------
// Persistent LSTM recurrence (R7 structure: LDS-staged coalesced h loads).
// Producer-flag sync; per-step single-use h buffers; relaxed atomic stores.
// Xp is bf16 (halves the streaming fetch).
// ---------------------------------------------------------------------------
__global__ __launch_bounds__(256, 1) void lstm_persist(
    const short* __restrict__ WhPh_e, const short* __restrict__ WhPh_w,
    const short* __restrict__ Xp_e, const short* __restrict__ Xp_w,
    const float* __restrict__ c0_in,
    ull* __restrict__ hq,        // [101][2][32][128] qwords
    short* __restrict__ outT,    // [2 lstm][100 t][512 u][32 b] bf16
    float* __restrict__ out_hc,  // he[32][512] then ce[32][512]
    unsigned* __restrict__ flags)// [0..63] per-block flags; [100] entry fence
{
  const int bx = blockIdx.x;
  const int l = bx >> 5;
  const int ublk = bx & 31;
  const int tid = threadIdx.x;
  const int w = tid >> 6, lane = tid & 63;
  const int uloc = lane >> 4;          // unit within wave (0..3)
  const int bn = lane & 15;            // batch (and bn+16)
  const int u_global = ublk*16 + w*4 + uloc;
  const int ob = (ublk*16 + w*4) * 4;  // o' base of wave
  const int qcol = ublk*4 + w;         // this wave's qword column

  const short* WhPh = l ? WhPh_w : WhPh_e;
  const short* Xp   = l ? Xp_w   : Xp_e;
  const unsigned* myfl = flags + l*32;

  __shared__ short hT[32][520];        // [b][k], +16B pad

  // one-time agent acquire: no cross-replay stale lines in L1/L2
  __hip_atomic_load(&flags[100], __ATOMIC_ACQUIRE, __HIP_MEMORY_SCOPE_AGENT);

  // preload weight A-frags
  short8v afr[16];
  {
    const short* wp = WhPh + (long)(ob + bn)*512 + uloc*8;
    #pragma unroll
    for (int ks = 0; ks < 16; ++ks)
      afr[ks] = *(const short8v*)(wp + ks*32);
  }
  // persistent cell state
  float c_s0 = c0_in[bn*512 + u_global];
  float c_s1 = c0_in[(bn+16)*512 + u_global];

  for (int t = 0; t < 100; ++t) {
    // Xp gathers issued early (bf16, 8B per thread)
    ull xq0 = *(const ull*)(Xp + ((long)(bn*100 + t))*2048 + u_global*4);
    ull xq1 = *(const ull*)(Xp + ((long)((bn+16)*100 + t))*2048 + u_global*4);
    // wait for all 32 producers of this lstm to have published h[t]
    if (t) {
      int ok;
      do {
        unsigned f = (lane < 32)
          ? __hip_atomic_load(&myfl[lane], __ATOMIC_RELAXED, __HIP_MEMORY_SCOPE_AGENT)
          : 0xffffffffu;
        ok = __all((int)(f >= (unsigned)t));
        if (!ok) __builtin_amdgcn_s_sleep(1);
      } while (!ok);
    }
    // stage h: coalesced loads of this step's single-use buffer -> LDS
    {
      const ull* hsrc = hq + (size_t)t*8192 + (l << 12);
      #pragma unroll
      for (int i = 0; i < 16; ++i) {
        int idx = tid + 256*i;         // 0..4095
        int b = idx >> 7, q = idx & 127;
        *(ull*)&hT[b][q*4] = hsrc[idx];
      }
    }
    __syncthreads();
    f32x4 acc0 = {}, acc1 = {};
    #pragma unroll
    for (int ks = 0; ks < 16; ++ks) {
      short8v b0 = *(const short8v*)&hT[bn][ks*32 + uloc*8];
      short8v b1 = *(const short8v*)&hT[bn+16][ks*32 + uloc*8];
      acc0 = __builtin_amdgcn_mfma_f32_16x16x32_bf16(afr[ks], b0, acc0, 0, 0, 0);
      acc1 = __builtin_amdgcn_mfma_f32_16x16x32_bf16(afr[ks], b1, acc1, 0, 0, 0);
    }
    // cell update (lane-local: acc regs 0..3 = gates i,f,g,o of this unit)
    float gi = acc0[0] + bf2f((short)(xq0 & 0xffffu));
    float gf = acc0[1] + bf2f((short)((xq0 >> 16) & 0xffffu));
    float gg = acc0[2] + bf2f((short)((xq0 >> 32) & 0xffffu));
    float go = acc0[3] + bf2f((short)((xq0 >> 48) & 0xffffu));
    c_s0 = sigf(gf)*c_s0 + sigf(gi)*tanhc(gg);
    float hv0 = sigf(go)*tanhc(c_s0);
    gi = acc1[0] + bf2f((short)(xq1 & 0xffffu));
    gf = acc1[1] + bf2f((short)((xq1 >> 16) & 0xffffu));
    gg = acc1[2] + bf2f((short)((xq1 >> 32) & 0xffffu));
    go = acc1[3] + bf2f((short)((xq1 >> 48) & 0xffffu));
    c_s1 = sigf(gf)*c_s1 + sigf(gi)*tanhc(gg);
    float hv1 = sigf(go)*tanhc(c_s1);

    short hb0 = f2bf(hv0), hb1 = f2bf(hv1);
    // pack 4 units (uloc 0..3 live in lanes bn, bn+16, bn+32, bn+48)
    unsigned p0 = (unsigned)(unsigned short)hb0;
    unsigned p1 = (unsigned)(unsigned short)hb1;
    unsigned a1 = __shfl_down((int)p0, 16), a2 = __shfl_down((int)p0, 32), a3 = __shfl_down((int)p0, 48);
    unsigned e1 = __shfl_down((int)p1, 16), e2 = __shfl_down((int)p1, 32), e3 = __shfl_down((int)p1, 48);
    if (uloc == 0) {
      ull q0 = ((ull)((a2 & 0xffffu) | (a3 << 16)) << 32) | ((p0 & 0xffffu) | (a1 << 16));
      ull q1 = ((ull)((e2 & 0xffffu) | (e3 << 16)) << 32) | ((p1 & 0xffffu) | (e1 << 16));
      ull* hd = hq + (size_t)(t+1)*8192 + (l << 12);
      __hip_atomic_store(&hd[(bn << 7) + qcol],      q0, __ATOMIC_RELAXED, __HIP_MEMORY_SCOPE_AGENT);
      __hip_atomic_store(&hd[((bn+16) << 7) + qcol], q1, __ATOMIC_RELAXED, __HIP_MEMORY_SCOPE_AGENT);
    }
    if (t < 99) {
      asm volatile("s_waitcnt vmcnt(0)" ::: "memory");  // own h-stores at L3
      __syncthreads();                                   // whole block drained
      if (tid == 0)
        __hip_atomic_store(&flags[bx], (unsigned)(t+1),
                           __ATOMIC_RELAXED, __HIP_MEMORY_SCOPE_AGENT);
    }
    // sequence output AFTER flag publication (off the critical path)
    short* od = outT + ((long)(l*100 + t)*512 + u_global)*32;
    od[bn]    = hb0;
    od[bn+16] = hb1;
    if (t == 99 && l == 0) {
      out_hc[bn*512 + u_global]              = hv0;
      out_hc[(bn+16)*512 + u_global]         = hv1;
      out_hc[16384 + bn*512 + u_global]      = c_s0;
      out_hc[16384 + (bn+16)*512 + u_global] = c_s1;
    }
  }
}

// transpose out sequences bf16 [lstm][t][u][b] -> bf16 [b][t][u]
__global__ __launch_bounds__(256) void transpose_out(
    const short* __restrict__ outT, short* __restrict__ out_e, short* __restrict__ out_w)
{
  __shared__ short tile[512][40];
  const int t = blockIdx.x, l = blockIdx.y;
  const short* src = outT + (long)(l*100 + t)*16384;
  const int tid = threadIdx.x;
  #pragma unroll
  for (int i = 0; i < 8; ++i) {
    int fi = tid + 256*i;
    int u = fi >> 2, b8 = (fi & 3)*8;
    *(short8v*)&tile[u][b8] = *(const short8v*)(src + fi*8);
  }
  __syncthreads();
  short* dst = l ? out_w : out_e;
  for (int b = 0; b < 32; ++b) {
    short* drow = dst + (long)(b*100 + t)*512;
    drow[tid]     = tile[tid][b];
    drow[tid+256] = tile[tid+256][b];
  }
}

__global__ void softmax_rows(float* __restrict__ P)
{
  int row  = blockIdx.x*4 + (threadIdx.x >> 6);
  int lane = threadIdx.x & 63;
  float* p = P + (long)row*128;
  float x0 = (lane      < 100) ? p[lane]    : -INFINITY;
  float x1 = (lane + 64 < 100) ? p[lane+64] : -INFINITY;
  float m = fmaxf(x0, x1);
  #pragma unroll
  for (int off = 32; off; off >>= 1) m = fmaxf(m, __shfl_xor(m, off));
  float e0 = (lane      < 100) ? __expf(x0 - m) : 0.f;
  float e1 = (lane + 64 < 100) ? __expf(x1 - m) : 0.f;
  float s = e0 + e1;
  #pragma unroll
  for (int off = 32; off; off >>= 1) s += __shfl_xor(s, off);
  float inv = 1.f / s;
  if (lane      < 100) p[lane]    = e0 * inv;
  if (lane + 64 < 100) p[lane+64] = e1 * inv;
}

// build bf16 feat rows [3168][2048] = [out_e | applied | enc[ctr_del] | out_w[ctr_ins]]
__global__ void feat_kernel(const short* __restrict__ out_e, const float* __restrict__ applied,
                            const float* __restrict__ enc,  const short* __restrict__ out_w,
                            const int* __restrict__ ctr_del, const int* __restrict__ ctr_ins,
                            short* __restrict__ feat)
{
  int n = blockIdx.x;                 // 0..3167
  int b = n / 99, t = n % 99;
  int tid = threadIdx.x;
  int seg = tid >> 6;
  int off = (tid & 63) * 8;
  short8v v;
  if (seg == 0) {
    v = *(const short8v*)(out_e + (long)(b*100 + t)*512 + off);
  } else if (seg == 3) {
    v = *(const short8v*)(out_w + (long)(b*100 + ctr_ins[n])*512 + off);
  } else {
    const float* s = (seg == 1) ? applied + (long)(b*100 + t)*512
                                : enc     + (long)(b*100 + ctr_del[n])*512;
    float4 v0 = *(const float4*)(s + off);
    float4 v1 = *(const float4*)(s + off + 4);
    v[0]=f2bf(v0.x); v[1]=f2bf(v0.y); v[2]=f2bf(v0.z); v[3]=f2bf(v0.w);
    v[4]=f2bf(v1.x); v[5]=f2bf(v1.y); v[6]=f2bf(v1.z); v[7]=f2bf(v1.w);
  }
  *(short8v*)(feat + (long)n*2048 + seg*512 + off) = v;
}

// ---------------------------------------------------------------------------
extern "C" void kernel_launch(void* const* d_in, const int* in_sizes, int n_in,
                              void* d_out, int out_size, void* d_ws, size_t ws_size,
                              hipStream_t stream)
{
  const int*   input_edits = (const int*)  d_in[0];
  const int*   simp_sent   = (const int*)  d_in[1];
  const float* enc   = (const float*)d_in[3];
  const float* h0    = (const float*)d_in[4];
  const float* c0    = (const float*)d_in[5];
  const float* emb   = (const float*)d_in[6];
  const float* Wi_e  = (const float*)d_in[7];
  const float* Wh_e  = (const float*)d_in[8];
  const float* bi_e  = (const float*)d_in[9];
  const float* bh_e  = (const float*)d_in[10];
  const float* Wi_w  = (const float*)d_in[11];
  const float* Wh_w  = (const float*)d_in[12];
  const float* bi_w  = (const float*)d_in[13];
  const float* bh_w  = (const float*)d_in[14];
  const float* Wp    = (const float*)d_in[15];
  const float* Wm    = (const float*)d_in[16];
  const float* bmv   = (const float*)d_in[17];
  const float* b_out = (const float*)d_in[18];
  float* out = (float*)d_out;

  float* ws = (float*)d_ws;
  size_t off = 0;
  auto alloc = [&](size_t n){ float* p = ws + off; off += (n + 63) & ~(size_t)63; return p; };

  short* WiPh_e   = (short*)alloc(262144);   // 2048*256 bf16
  short* WiPh_w   = (short*)alloc(262144);
  float* biasP_e  = alloc(2048);
  float* biasP_w  = alloc(2048);
  short* WhPh_e   = (short*)alloc(524288);   // 2048*512 bf16
  short* WhPh_w   = (short*)alloc(524288);
  short* Xp_e     = (short*)alloc(3276800);  // 3200*2048 bf16
  short* Xp_w     = (short*)alloc(3276800);
  short* outT     = (short*)alloc(1638400);  // 2*100*512*32 bf16
  short* out_e    = (short*)alloc(819200);   // 3200*512 bf16
  short* out_w    = (short*)alloc(819200);
  ull*   hq       = (ull*)alloc(101*8192*2); // 101 step buffers x 64KB
  unsigned* bar   = (unsigned*)alloc(128);   // flags[0..63] + entry slot [100]
  float* Pbuf     = alloc(3200*128);
  int*   ctr_del  = (int*)alloc(3168);
  int*   ctr_ins  = (int*)alloc(3168);
  short* Wph      = (short*)alloc(131072);   // 512*512 bf16
  short* Wmh      = (short*)alloc(262144);   // 256*2048 bf16
  float* key      = alloc(3200*512);
  float* applied  = alloc(3200*512);
  short* logith   = (short*)alloc(47520000); // 3168*30000 bf16 logits (190MB)
  float2* partial = (float2*)alloc(3168*NTIL*2);
  // overlays (lifetimes disjoint, stream-ordered):
  short* feath    = (short*)Xp_e;            // 3168*2048 bf16, after recurrence
  short* hmlph    = (short*)Xp_w;            // 3168*256 bf16, after MLP

  // 1) weight prep (both LSTMs) + misc prep (convs, h0, flags, counters)
  prep_permute<<<dim3(4096,2), 256, 0, stream>>>(
      Wi_e, Wh_e, bi_e, bh_e, Wi_w, Wh_w, bi_w, bh_w,
      WiPh_e, WhPh_e, biasP_e, WiPh_w, WhPh_w, biasP_w);
  misc_prep<<<801, 256, 0, stream>>>(Wp, Wm, h0, input_edits,
                                     Wph, Wmh, hq, bar, ctr_del, ctr_ins);

  // 2) Xproj both LSTMs, one launch, bf16 out
  xproj_mfma<<<dim3(25,16,2), 256, 0, stream>>>(
      emb, input_edits, simp_sent, WiPh_e, WiPh_w, biasP_e, biasP_w, Xp_e, Xp_w);

  // 3) recurrence: ONE persistent kernel, producer-flag sync, LDS-staged h
  lstm_persist<<<LSTM_BLOCKS, 256, 0, stream>>>(
      WhPh_e, WhPh_w, Xp_e, Xp_w, c0, hq, outT, out + 95040000L, bar);

  // 4) transpose sequences to bf16 [b][t][u]
  transpose_out<<<dim3(100,2), 256, 0, stream>>>(outT, out_e, out_w);

  // 5) key = out_e @ Wp^T  (MFMA)
  gemm_mfma<0,0,0,0,0><<<dim3(25,4), 256, 0, stream>>>(
      out_e, nullptr, Wph, nullptr, key, 3200, 512, 512, 512, 512);

  // 6) attention (f32)
  gemm_f32<1><<<dim3(2,2,32), 256, 0, stream>>>(
      key, enc, Pbuf, 100, 100, 512, 512, 512, 128, 51200, 51200, 12800);
  softmax_rows<<<800, 256, 0, stream>>>(Pbuf);
  gemm_f32<0><<<dim3(8,2,32), 256, 0, stream>>>(
      Pbuf, enc, applied, 100, 512, 100, 128, 512, 512, 12800, 51200, 51200);

  // 7) feat(bf16) + MLP(MFMA, tanh, bf16 out)
  feat_kernel<<<3168, 256, 0, stream>>>(out_e, applied, enc, out_w, ctr_del, ctr_ins, feath);
  gemm_mfma<0,0,1,1,1><<<dim3(25,2), 256, 0, stream>>>(
      feath, nullptr, Wmh, bmv, hmlph, 3168, 256, 2048, 2048, 256);

  // 8) logits (MFMA, B cvt from f32 emb, bf16 out + LSE partials) + fused sub
  logits_mfma_partial<<<dim3(25, NTIL), 256, 0, stream>>>(
      hmlph, emb, b_out, logith, partial);
  sub_lse_fused<<<3168, 256, 0, stream>>>(logith, partial, out);
}